// Round 5
// baseline (5779075.000 us; speedup 1.0000x reference)
//
#include <hip/hip_runtime.h>
#include <math.h>

#define KN 1024
#define KB 128
#define KDT 0.1f
#define KSTEPS 10
#define KMAGIC 0xB0000000u      // > 0xAAAAAAAA poison: stale poison never passes >=
#define DMAGIC 0xD0000000u      // detection-slot magic (poison-distinguishable)
#define PI_F 3.14159265358979f
#define TWO_PI_F 6.28318530717959f

typedef __attribute__((ext_vector_type(8))) short short8;
typedef __attribute__((ext_vector_type(4))) float floatx4;
typedef unsigned long long u64;

__device__ __forceinline__ unsigned short f2bf(float f) {
    unsigned u = __float_as_uint(f);
    u += 0x7FFF + ((u >> 16) & 1);          // round-to-nearest-even
    return (unsigned short)(u >> 16);
}

// X layout (fragment order, per group g; 16384 dwords per group).
// Element (b15 = b&15, k): chunk=k>>5, quad=(k>>3)&3, jj=(k>>1)&3, p=k&1
//   dword idx = g*16384 + chunk*512 + jj*128 + quad*32 + b15*2 + p
// Chunk c written entirely by producer block (g, ib=c) (its 32 cols).
// Consumer wave kq reads chunks kq*4..kq*4+3 -> exactly 4 producer blocks.
__device__ __forceinline__ unsigned xidx(int grp, int b15, int k) {
    return (unsigned)(grp * 16384 + (k >> 5) * 512 + ((k >> 1) & 3) * 128 +
                      ((k >> 3) & 3) * 32 + b15 * 2 + (k & 1));
}

// ---- same-XCD (L2-coherent) primitives: sc0 = bypass L1, serve from L2.
__device__ __forceinline__ unsigned ld_u32_sc0(const unsigned* p) {
    unsigned r;
    asm volatile("global_load_dword %0, %1, off sc0\n\t"
                 "s_waitcnt vmcnt(0)"
                 : "=v"(r) : "v"(p) : "memory");
    return r;
}
__device__ __forceinline__ void st_u32_sc0(unsigned* p, unsigned v) {
    asm volatile("global_store_dword %0, %1, off sc0" :: "v"(p), "v"(v) : "memory");
}

// Single kernel, plain launch (graph-capturable).
// Grid 256 = 8 groups x 32 i-blocks; block 512 thr = 8 waves.
// R5 == R4 with the s_sleep literal-constant compile fix.
//  (1) THREE rotating X buffers (was 2). With 2 buffers, X(s+1) overwrites
//      X(s-1) but the transitive flag chain only certifies all blocks done
//      with step-(s-2) READS — one step short => rare torn read (R2's ghost).
//      With 3, X(s+1) overwrites X(s-2): P stores X(s+1) after wait(s) <=
//      flag_Q(s) <= every block's flag(s-1) <= every block's step-(s-2)
//      A-loads retired (loads feed MFMA before that flag's barrier). Airtight.
//  (2) grp = blockIdx.x & 7 (round-robin dispatch => group likely XCD-local)
//      + runtime XCC_ID detection: if all 32 blocks of the group share an
//      XCD, the X/flag exchange runs through that XCD's L2 (sc0 ops, ~4x
//      lower latency, 4.3 TB/s); else byte-exact R8 agent-scope path.
//      Decision is group-uniform (same 32 inputs, same predicate); detection
//      poll has no timeout — all 256 blocks are co-resident (256 CUs).
__global__ __launch_bounds__(512)
void k_main(const float* __restrict__ theta0,
            const float* __restrict__ Kmat,
            const float* __restrict__ omega,
            const float* __restrict__ kg,
            float* __restrict__ out_theta,
            float* __restrict__ out_coh,
            unsigned* __restrict__ flags,        // 256: step flags (path-flavored)
            unsigned* __restrict__ det,          // 256: XCC_ID posts (agent)
            unsigned* __restrict__ eflags,       // 256: epilogue flags (agent)
            float* __restrict__ acc,             // coherence accum: 2*128 slots, 64B stride
            unsigned* __restrict__ xbuf)         // 3 rotating buffers of KB*KN dwords
{
    const int grp = blockIdx.x & 7;          // XCD-local grouping (heuristic only)
    const int ib  = blockIdx.x >> 3;
    const int b0  = grp * 16;
    const int i0  = ib * 32;

    const int tid  = threadIdx.x;
    const int lane = tid & 63;
    const int kq   = tid >> 6;              // wave = k-eighth
    const int r16  = lane & 15;
    const int quad = lane >> 4;

    __shared__ float ldsY[8][2][16][34];    // [kq][S/C][m][il+pad] 34.8 KB

    // ---- post own XCC id (agent, fire-and-forget; consumers poll the data,
    // DMAGIC-tagged so poison/stale can't alias — ws re-poisoned per call)
    unsigned xcc;
    asm volatile("s_getreg_b32 %0, hwreg(HW_REG_XCC_ID)" : "=s"(xcc));
    xcc &= 0xfu;
    if (tid == 0)
        __hip_atomic_store(&det[grp * 32 + ib], DMAGIC | xcc,
                           __ATOMIC_RELAXED, __HIP_MEMORY_SCOPE_AGENT);

    // group leader zeroes its coherence accumulators (drained by the pre-flag
    // __syncthreads below, i.e. before flag(0) releases anyone; epilogue adds
    // trail by the whole step loop)
    if (ib == 0 && tid < 16) {
        __hip_atomic_store(&acc[(b0 + tid) * 16], 0.f, __ATOMIC_RELAXED,
                           __HIP_MEMORY_SCOPE_AGENT);
        __hip_atomic_store(&acc[2048 + (b0 + tid) * 16], 0.f, __ATOMIC_RELAXED,
                           __HIP_MEMORY_SCOPE_AGENT);
    }

    // ---- per-thread theta state (block-private tile, 1 elem/thread).
    const int eb = b0 + (tid >> 5);          // batch
    const int ei = i0 + (tid & 31);          // column
    float th_reg = theta0[(size_t)eb * KN + ei];
    const float omg = omega[ei];
    float sn, cs;
    __sincosf(th_reg, &sn, &cs);
    const unsigned xoff = xidx(grp, tid >> 5, ei);
    const float scale = kg[0] * (1.0f / (float)KN);

    // ---- B fragments (both wi) fp32->bf16 into registers; K symmetric.
    // (long-latency HBM loads overlap the det-visibility window)
    short8 bfrag[2][4];
    #pragma unroll
    for (int wi = 0; wi < 2; ++wi) {
        const float* kp = Kmat + (size_t)(i0 + wi * 16 + r16) * KN + kq * 128 + quad * 8;
        #pragma unroll
        for (int it = 0; it < 4; ++it) {
            const float4 v0 = *reinterpret_cast<const float4*>(kp + it * 32);
            const float4 v1 = *reinterpret_cast<const float4*>(kp + it * 32 + 4);
            short8 b_;
            b_[0] = (short)f2bf(v0.x); b_[1] = (short)f2bf(v0.y);
            b_[2] = (short)f2bf(v0.z); b_[3] = (short)f2bf(v0.w);
            b_[4] = (short)f2bf(v1.x); b_[5] = (short)f2bf(v1.y);
            b_[6] = (short)f2bf(v1.z); b_[7] = (short)f2bf(v1.w);
            bfrag[wi][it] = b_;
        }
    }

    // ---- detection poll (agent; no timeout — co-residency guarantees posts)
    const unsigned mydet = DMAGIC | xcc;
    bool fast;
    {
        unsigned v = mydet;
        for (;;) {
            if (lane < 32)
                v = __hip_atomic_load(&det[grp * 32 + lane],
                                      __ATOMIC_RELAXED, __HIP_MEMORY_SCOPE_AGENT);
            if (__ballot((v & 0xFFFFFFF0u) == DMAGIC) == ~0ull) break;
            __builtin_amdgcn_s_sleep(2);
        }
        fast = (__ballot(v == mydet) == ~0ull);   // group-uniform decision
        asm volatile("" ::: "memory");
    }

    // ---- publish X(0) into buffer 0 + flag(0)
    unsigned* xb[3] = {xbuf, xbuf + (size_t)KB * KN, xbuf + 2 * (size_t)KB * KN};
    {
        const unsigned pack = (unsigned)f2bf(sn) | ((unsigned)f2bf(cs) << 16);
        if (fast) {
            st_u32_sc0(&xb[0][xoff], pack);
            asm volatile("s_waitcnt vmcnt(0)" ::: "memory");  // asm stores untracked by compiler
        } else {
            __hip_atomic_store(&xb[0][xoff], pack,
                               __ATOMIC_RELAXED, __HIP_MEMORY_SCOPE_AGENT);
        }
    }
    __syncthreads();                         // drains tracked stores (and acc zeros)
    if (tid == 0) {
        if (fast) st_u32_sc0(&flags[grp * 32 + ib], KMAGIC + 0u);
        else __hip_atomic_store(&flags[grp * 32 + ib], KMAGIC + 0u,
                                __ATOMIC_RELAXED, __HIP_MEMORY_SCOPE_AGENT);
    }

    float s2 = sn, c2 = cs;
    for (int s = 0; s < KSTEPS; ++s) {
        const unsigned tgt = KMAGIC + (unsigned)s;

        // ---- per-wave dataflow wait: lanes 0..3 poll this wave's 4 producer
        // block-flags (one 128 B line). Monotone >= compare.
        {
            unsigned polls = 0;
            for (;;) {
                unsigned v = tgt;
                if (lane < 4) {
                    const unsigned* fp = &flags[grp * 32 + kq * 4 + lane];
                    v = fast ? ld_u32_sc0(fp)
                             : __hip_atomic_load(fp, __ATOMIC_RELAXED,
                                                 __HIP_MEMORY_SCOPE_AGENT);
                }
                if (__ballot(v >= tgt) == ~0ull) break;
                if (++polls > 4000000u) break;   // failsafe: fail visibly, not hang
                __builtin_amdgcn_s_sleep(1);
            }
            asm volatile("" ::: "memory");       // no load hoisting above the poll
        }

        // ---- A stage: 16 dense coherent u64 loads (512 B/wave-instr)
        const u64* xg = (const u64*)xb[s % 3] + grp * 8192 + kq * 1024 + lane;
        u64 aw[4][4];
        if (fast) {
            #pragma unroll
            for (int it = 0; it < 4; ++it) {
                const u64* pa = xg + it * 256;
                asm volatile(
                    "global_load_dwordx2 %0, %4, off sc0\n\t"
                    "global_load_dwordx2 %1, %4, off offset:512 sc0\n\t"
                    "global_load_dwordx2 %2, %4, off offset:1024 sc0\n\t"
                    "global_load_dwordx2 %3, %4, off offset:1536 sc0"
                    : "=&v"(aw[it][0]), "=&v"(aw[it][1]),
                      "=&v"(aw[it][2]), "=&v"(aw[it][3])
                    : "v"(pa));
            }
            asm volatile("s_waitcnt vmcnt(0)" ::: "memory");
            __builtin_amdgcn_sched_barrier(0);   // rule #18: no hoist past waitcnt
        } else {
            #pragma unroll
            for (int it = 0; it < 4; ++it)
                #pragma unroll
                for (int jj = 0; jj < 4; ++jj)
                    aw[it][jj] = __hip_atomic_load((u64*)(xg + it * 256 + jj * 64),
                                                   __ATOMIC_RELAXED,
                                                   __HIP_MEMORY_SCOPE_AGENT);
        }

        // ---- extract + MFMA (both wi subtiles)
        floatx4 accS[2] = {{0.f,0.f,0.f,0.f},{0.f,0.f,0.f,0.f}};
        floatx4 accC[2] = {{0.f,0.f,0.f,0.f},{0.f,0.f,0.f,0.f}};
        #pragma unroll
        for (int it = 0; it < 4; ++it) {
            short8 a_s, a_c;
            #pragma unroll
            for (int jj = 0; jj < 4; ++jj) {
                unsigned lo = (unsigned)aw[it][jj];
                unsigned hi = (unsigned)(aw[it][jj] >> 32);
                a_s[jj * 2]     = (short)(lo & 0xffffu);
                a_c[jj * 2]     = (short)(lo >> 16);
                a_s[jj * 2 + 1] = (short)(hi & 0xffffu);
                a_c[jj * 2 + 1] = (short)(hi >> 16);
            }
            #pragma unroll
            for (int wi = 0; wi < 2; ++wi) {
                accS[wi] = __builtin_amdgcn_mfma_f32_16x16x32_bf16(a_s, bfrag[wi][it], accS[wi], 0, 0, 0);
                accC[wi] = __builtin_amdgcn_mfma_f32_16x16x32_bf16(a_c, bfrag[wi][it], accC[wi], 0, 0, 0);
            }
        }
        #pragma unroll
        for (int wi = 0; wi < 2; ++wi)
            #pragma unroll
            for (int r = 0; r < 4; ++r) {
                ldsY[kq][0][quad * 4 + r][wi * 16 + r16] = accS[wi][r];  // D[m=quad*4+r][n=r16]
                ldsY[kq][1][quad * 4 + r][wi * 16 + r16] = accC[wi][r];
            }
        __syncthreads();

        // ---- Euler update + branch-wrap (1 elem/thread)
        {
            const int bl = tid >> 5, ilo = tid & 31;
            float Ys = 0.f, Yc = 0.f;
            #pragma unroll
            for (int q = 0; q < 8; ++q) {
                Ys += ldsY[q][0][bl][ilo];
                Yc += ldsY[q][1][bl][ilo];
            }
            const float coupling = cs * Ys - sn * Yc;   // sum_j K[i,j] sin(th_j - th_i)
            float tn = th_reg + KDT * (omg + scale * coupling);
            __sincosf(tn, &s2, &c2);                    // also next step's (sn,cs)
            if (tn > PI_F)       tn -= TWO_PI_F;        // == atan2f(s2,c2) to ~1e-7
            else if (tn < -PI_F) tn += TWO_PI_F;
            th_reg = tn;
            sn = s2; cs = c2;
        }
        if (s < KSTEPS - 1) {
            const unsigned pack = (unsigned)f2bf(s2) | ((unsigned)f2bf(c2) << 16);
            unsigned* xn = &xb[(s + 1) % 3][xoff];
            if (fast) {
                st_u32_sc0(xn, pack);
                asm volatile("s_waitcnt vmcnt(0)" ::: "memory");
            } else {
                __hip_atomic_store(xn, pack,
                                   __ATOMIC_RELAXED, __HIP_MEMORY_SCOPE_AGENT);
            }
            __syncthreads();                 // drains X(s+1) stores; guards ldsY reuse
            if (tid == 0) {
                if (fast) st_u32_sc0(&flags[grp * 32 + ib], KMAGIC + (unsigned)(s + 1));
                else __hip_atomic_store(&flags[grp * 32 + ib], KMAGIC + (unsigned)(s + 1),
                                        __ATOMIC_RELAXED, __HIP_MEMORY_SCOPE_AGENT);
            }
        } else {
            out_theta[(size_t)eb * KN + ei] = th_reg;
        }
    }

    // ---- coherence: block-local reduce over its 32 cols, then padded atomics
    // (epilogue is off the critical path: keep proven agent-scope protocol)
    __syncthreads();                         // epilogue ldsY reads done
    float* red = &ldsY[0][0][0][0];
    red[tid]       = s2;                     // == sin(theta_final) to ~1e-7
    red[512 + tid] = c2;
    __syncthreads();
    if (tid < 16) {
        float ss = 0.f, cc = 0.f;
        #pragma unroll
        for (int il2 = 0; il2 < 32; ++il2) {
            ss += red[tid * 32 + il2];
            cc += red[512 + tid * 32 + il2];
        }
        atomicAdd(&acc[(b0 + tid) * 16], ss);           // 64B-stride slots
        atomicAdd(&acc[2048 + (b0 + tid) * 16], cc);
    }
    __syncthreads();                         // drain atomics (vmcnt(0))
    if (tid == 0)
        __hip_atomic_store(&eflags[grp * 32 + ib], KMAGIC,
                           __ATOMIC_RELAXED, __HIP_MEMORY_SCOPE_AGENT);

    // group leader: wait all 32 blocks' adds, then write out_coh
    if (ib == 0) {
        if (tid < 64) {
            unsigned polls = 0;
            for (;;) {
                unsigned v = KMAGIC;
                if (lane < 32)
                    v = __hip_atomic_load(&eflags[grp * 32 + lane],
                                          __ATOMIC_RELAXED, __HIP_MEMORY_SCOPE_AGENT);
                if (__ballot(v >= KMAGIC) == ~0ull) break;
                if (++polls > 4000000u) break;
                __builtin_amdgcn_s_sleep(2);
            }
        }
        asm volatile("" ::: "memory");       // acc reads must not hoist above poll
        __syncthreads();
        if (tid < 16) {
            float sv = __hip_atomic_load(&acc[(b0 + tid) * 16],
                                         __ATOMIC_RELAXED, __HIP_MEMORY_SCOPE_AGENT);
            float cv = __hip_atomic_load(&acc[2048 + (b0 + tid) * 16],
                                         __ATOMIC_RELAXED, __HIP_MEMORY_SCOPE_AGENT);
            float sm = sv * (1.0f / (float)KN);
            float cm = cv * (1.0f / (float)KN);
            out_coh[b0 + tid] = sqrtf(cm * cm + sm * sm);
        }
    }
}

extern "C" void kernel_launch(void* const* d_in, const int* in_sizes, int n_in,
                              void* d_out, int out_size, void* d_ws, size_t ws_size,
                              hipStream_t stream)
{
    (void)in_sizes; (void)n_in; (void)out_size; (void)ws_size;

    const float* theta0 = (const float*)d_in[0];
    const float* Kmat   = (const float*)d_in[1];
    const float* omega  = (const float*)d_in[2];
    const float* kg     = (const float*)d_in[3];

    float* out_theta = (float*)d_out;                    // 128*1024 f32
    float* out_coh   = out_theta + (size_t)KB * KN;      // +128 f32

    // ws: flags[256]@0 | det[256]@1024 | eflags[256]@2048 | acc 16 KB @4096 |
    //     xbuf @32768: 3 rotating buffers of KB*KN dwords (512 KB each).
    // Harness re-poisons ws with 0xAAAAAAAA each call: poison < KMAGIC,
    // poison's high nibble != 0xD => all protocol slots self-reset.
    unsigned* flags  = (unsigned*)d_ws;
    unsigned* det    = (unsigned*)((char*)d_ws + 1024);
    unsigned* eflags = (unsigned*)((char*)d_ws + 2048);
    float* acc       = (float*)((char*)d_ws + 4096);
    unsigned* xbuf   = (unsigned*)((char*)d_ws + 32768);

    k_main<<<256, 512, 0, stream>>>(theta0, Kmat, omega, kg,
                                    out_theta, out_coh, flags, det, eflags,
                                    acc, xbuf);
}

// Round 6
// 110.936 us; speedup vs baseline: 52093.7654x; 52093.7654x over previous
//
#include <hip/hip_runtime.h>
#include <math.h>

#define KN 1024
#define KB 128
#define KDT 0.1f
#define KSTEPS 10
#define KMAGIC 0xB0000000u      // > 0xAAAAAAAA poison: stale poison never passes >=
#define PI_F 3.14159265358979f
#define TWO_PI_F 6.28318530717959f

typedef __attribute__((ext_vector_type(8))) short short8;
typedef __attribute__((ext_vector_type(4))) float floatx4;
typedef unsigned long long u64;

__device__ __forceinline__ unsigned short f2bf(float f) {
    unsigned u = __float_as_uint(f);
    u += 0x7FFF + ((u >> 16) & 1);          // round-to-nearest-even
    return (unsigned short)(u >> 16);
}

// X layout (fragment order, per group g = b>>4; 16384 dwords per group).
// Element (b15 = b&15, k): chunk=k>>5, quad=(k>>3)&3, jj=(k>>1)&3, p=k&1
//   dword idx = g*16384 + chunk*512 + jj*128 + quad*32 + b15*2 + p
// Chunk c is written entirely by producer block (g, ib=c) (its 32 cols).
// Consumer wave kq reads chunks kq*4..kq*4+3 -> 4 producer blocks (32 waves).
__device__ __forceinline__ unsigned xidx(int grp, int b15, int k) {
    return (unsigned)(grp * 16384 + (k >> 5) * 512 + ((k >> 1) & 3) * 128 +
                      ((k >> 3) & 3) * 32 + b15 * 2 + (k & 1));
}

// Single kernel, plain launch (graph-capturable).
// Grid 256 = 8 batch-groups(16 b) x 32 i-blocks(32 cols); block 512 thr = 8 waves.
// R6 = proven R8 skeleton (agent-scope flag dataflow, narrow flag-line polls,
// data loaded once) + two audited deltas:
//  (1) THREE rotating X buffers. With 2, X(s+1) overwrites X(s-1), but the
//      flag chain only certifies step-(s-2) reads retired — one step short
//      (the R2 post-timing ghost). With 3, X(s+1) overwrites X(s-2):
//      P stores X(s+1) after wait(s) <= 32 producer-wave flags(s), each set
//      after that wave's wait(s-1) <= union covers ALL 256 group waves'
//      flags(s-1), each set after that wave's step-(s-1) A-loads retired
//      (they feed MFMA before the flag) >= step-(s-2) reads retired. Airtight.
//  (2) PER-WAVE producer flags: each wave drains its own X store
//      (s_waitcnt vmcnt(0)) and lane 0 signals right after its Euler slice.
//      Removes the block-wide join + 2nd __syncthreads from the signal path.
//      ldsY double-buffered -> exactly one barrier/step (pre-Euler join).
//      Compiler fence after every poll: relaxed A-loads must not hoist above
//      the flag observation (rule #18 class hazard; R2 lacked this).
// Dead-end notes: data-polling floods fabric (R9/R3: FETCH 2-3x, +VALUBusy);
// sc0 global ops are NOT cross-CU coherent on gfx950 (R5: 5.8 s visibility
// stalls) — XCD-L2 exchange is unreachable from HIP source.
__global__ __launch_bounds__(512)
void k_main(const float* __restrict__ theta0,
            const float* __restrict__ Kmat,
            const float* __restrict__ omega,
            const float* __restrict__ kg,
            float* __restrict__ out_theta,
            float* __restrict__ out_coh,
            unsigned* __restrict__ flags,        // 2048 wave flags: [grp*256+ib*8+kq]
            unsigned* __restrict__ eflags,       // 256 epilogue block flags
            float* __restrict__ acc,             // coherence accum: 2*128 slots, 64B stride
            unsigned* __restrict__ xbuf)         // 3 rotating buffers of KB*KN dwords
{
    const int grp = blockIdx.x >> 5;
    const int b0  = grp * 16;
    const int ib  = blockIdx.x & 31;
    const int i0  = ib * 32;

    const int tid  = threadIdx.x;
    const int lane = tid & 63;
    const int kq   = tid >> 6;              // wave = k-eighth
    const int r16  = lane & 15;
    const int quad = lane >> 4;

    __shared__ float ldsY[2][8][2][16][34]; // [buf][kq][S/C][m][il+pad] 69.6 KB

    // Group leader's wave 0 zeroes its coherence accumulators BEFORE its X(0)
    // publication: the zeros drain in the same per-wave vmcnt(0) as X(0), so
    // leader-wave0's flag(0) orders them before anyone's step-0 barrier, and
    // epilogue adds trail step 9.
    if (ib == 0 && tid < 16) {
        __hip_atomic_store(&acc[(b0 + tid) * 16], 0.f, __ATOMIC_RELAXED,
                           __HIP_MEMORY_SCOPE_AGENT);
        __hip_atomic_store(&acc[2048 + (b0 + tid) * 16], 0.f, __ATOMIC_RELAXED,
                           __HIP_MEMORY_SCOPE_AGENT);
    }

    // ---- per-thread theta state (block-private tile, 1 elem/thread).
    const int eb = b0 + (tid >> 5);          // batch
    const int ei = i0 + (tid & 31);          // column
    float th_reg = theta0[(size_t)eb * KN + ei];
    const float omg = omega[ei];
    float sn, cs;
    __sincosf(th_reg, &sn, &cs);
    const unsigned xoff = xidx(grp, tid >> 5, ei);
    unsigned* xb[3] = {xbuf, xbuf + (size_t)KB * KN, xbuf + 2 * (size_t)KB * KN};

    // publish X(0) + per-wave flag(0) as early as possible
    __hip_atomic_store(&xb[0][xoff],
                       (unsigned)f2bf(sn) | ((unsigned)f2bf(cs) << 16),
                       __ATOMIC_RELAXED, __HIP_MEMORY_SCOPE_AGENT);
    const int myflag = grp * 256 + ib * 8 + kq;
    asm volatile("s_waitcnt vmcnt(0)" ::: "memory");     // drain this wave's X(0)
    if (lane == 0)
        __hip_atomic_store(&flags[myflag], KMAGIC + 0u,
                           __ATOMIC_RELAXED, __HIP_MEMORY_SCOPE_AGENT);
    const float scale = kg[0] * (1.0f / (float)KN);

    // ---- B fragments (both wi) fp32->bf16 into registers; K symmetric.
    // (HBM loads overlap other blocks' X(0)/flag(0) visibility window)
    short8 bfrag[2][4];
    #pragma unroll
    for (int wi = 0; wi < 2; ++wi) {
        const float* kp = Kmat + (size_t)(i0 + wi * 16 + r16) * KN + kq * 128 + quad * 8;
        #pragma unroll
        for (int it = 0; it < 4; ++it) {
            const float4 v0 = *reinterpret_cast<const float4*>(kp + it * 32);
            const float4 v1 = *reinterpret_cast<const float4*>(kp + it * 32 + 4);
            short8 b_;
            b_[0] = (short)f2bf(v0.x); b_[1] = (short)f2bf(v0.y);
            b_[2] = (short)f2bf(v0.z); b_[3] = (short)f2bf(v0.w);
            b_[4] = (short)f2bf(v1.x); b_[5] = (short)f2bf(v1.y);
            b_[6] = (short)f2bf(v1.z); b_[7] = (short)f2bf(v1.w);
            bfrag[wi][it] = b_;
        }
    }

    // Per-wave dataflow wait: lanes 0..31 poll this wave's 32 producer-wave
    // flags (8 waves x 4 blocks, contiguous -> one 128 B line). Monotone >=.
    auto wait_waves = [&](unsigned tgt) {
        unsigned polls = 0;
        for (;;) {
            unsigned v = tgt;
            if (lane < 32)
                v = __hip_atomic_load(&flags[grp * 256 + kq * 32 + lane],
                                      __ATOMIC_RELAXED, __HIP_MEMORY_SCOPE_AGENT);
            if (__ballot(v >= tgt) == ~0ull) break;
            if (++polls > 4000000u) break;   // failsafe: fail visibly, not hang
            __builtin_amdgcn_s_sleep(2);
        }
        asm volatile("" ::: "memory");       // A-loads must not hoist above poll
    };

    float s2 = sn, c2 = cs;
    for (int s = 0; s < KSTEPS; ++s) {
        wait_waves(KMAGIC + (unsigned)s);    // X(s) chunks for this wave ready

        // ---- A stage: 16 dense coherent u64 loads (512 B/wave-instr)
        const u64* xg = (const u64*)xb[s % 3] + grp * 8192 + kq * 1024 + lane;
        u64 aw[4][4];
        #pragma unroll
        for (int it = 0; it < 4; ++it)
            #pragma unroll
            for (int jj = 0; jj < 4; ++jj)
                aw[it][jj] = __hip_atomic_load((u64*)(xg + it * 256 + jj * 64),
                                               __ATOMIC_RELAXED,
                                               __HIP_MEMORY_SCOPE_AGENT);
        // ---- extract + MFMA (both wi subtiles)
        floatx4 accS[2] = {{0.f,0.f,0.f,0.f},{0.f,0.f,0.f,0.f}};
        floatx4 accC[2] = {{0.f,0.f,0.f,0.f},{0.f,0.f,0.f,0.f}};
        #pragma unroll
        for (int it = 0; it < 4; ++it) {
            short8 a_s, a_c;
            #pragma unroll
            for (int jj = 0; jj < 4; ++jj) {
                unsigned lo = (unsigned)aw[it][jj];
                unsigned hi = (unsigned)(aw[it][jj] >> 32);
                a_s[jj * 2]     = (short)(lo & 0xffffu);
                a_c[jj * 2]     = (short)(lo >> 16);
                a_s[jj * 2 + 1] = (short)(hi & 0xffffu);
                a_c[jj * 2 + 1] = (short)(hi >> 16);
            }
            #pragma unroll
            for (int wi = 0; wi < 2; ++wi) {
                accS[wi] = __builtin_amdgcn_mfma_f32_16x16x32_bf16(a_s, bfrag[wi][it], accS[wi], 0, 0, 0);
                accC[wi] = __builtin_amdgcn_mfma_f32_16x16x32_bf16(a_c, bfrag[wi][it], accC[wi], 0, 0, 0);
            }
        }
        const int lb = s & 1;               // ldsY double-buffer select
        #pragma unroll
        for (int wi = 0; wi < 2; ++wi)
            #pragma unroll
            for (int r = 0; r < 4; ++r) {
                ldsY[lb][kq][0][quad * 4 + r][wi * 16 + r16] = accS[wi][r];
                ldsY[lb][kq][1][quad * 4 + r][wi * 16 + r16] = accC[wi][r];
            }
        __syncthreads();                     // the ONE barrier: join for Euler

        // ---- Euler update + branch-wrap (1 elem/thread)
        {
            const int bl = tid >> 5, ilo = tid & 31;
            float Ys = 0.f, Yc = 0.f;
            #pragma unroll
            for (int q = 0; q < 8; ++q) {
                Ys += ldsY[lb][q][0][bl][ilo];
                Yc += ldsY[lb][q][1][bl][ilo];
            }
            const float coupling = cs * Ys - sn * Yc;   // sum_j K[i,j] sin(th_j - th_i)
            float tn = th_reg + KDT * (omg + scale * coupling);
            __sincosf(tn, &s2, &c2);                    // also next step's (sn,cs)
            if (tn > PI_F)       tn -= TWO_PI_F;        // == atan2f(s2,c2) to ~1e-7
            else if (tn < -PI_F) tn += TWO_PI_F;
            th_reg = tn;
            sn = s2; cs = c2;
        }
        if (s < KSTEPS - 1) {
            // per-wave publish: own X(s+1) store -> wave-local drain -> flag
            __hip_atomic_store(&xb[(s + 1) % 3][xoff],
                               (unsigned)f2bf(s2) | ((unsigned)f2bf(c2) << 16),
                               __ATOMIC_RELAXED, __HIP_MEMORY_SCOPE_AGENT);
            asm volatile("s_waitcnt vmcnt(0)" ::: "memory");
            if (lane == 0)
                __hip_atomic_store(&flags[myflag], KMAGIC + (unsigned)(s + 1),
                                   __ATOMIC_RELAXED, __HIP_MEMORY_SCOPE_AGENT);
        } else {
            out_theta[(size_t)eb * KN + ei] = th_reg;
        }
    }

    // ---- coherence: block-local reduce over its 32 cols, then padded atomics
    __syncthreads();                         // all waves past Euler(9) ldsY reads
    float* red = &ldsY[0][0][0][0][0];       // buf0: last read at Euler(8), all joined
    red[tid]       = s2;                     // == sin(theta_final) to ~1e-7
    red[512 + tid] = c2;
    __syncthreads();
    if (tid < 16) {
        float ss = 0.f, cc = 0.f;
        #pragma unroll
        for (int il2 = 0; il2 < 32; ++il2) {
            ss += red[tid * 32 + il2];
            cc += red[512 + tid * 32 + il2];
        }
        atomicAdd(&acc[(b0 + tid) * 16], ss);           // 64B-stride slots
        atomicAdd(&acc[2048 + (b0 + tid) * 16], cc);
    }
    __syncthreads();                         // drains wave0's atomics (vmcnt(0))
    if (tid == 0)
        __hip_atomic_store(&eflags[blockIdx.x], KMAGIC,
                           __ATOMIC_RELAXED, __HIP_MEMORY_SCOPE_AGENT);

    // group leader: wait all 32 blocks' adds, then write out_coh
    if (ib == 0) {
        if (tid < 64) {
            unsigned polls = 0;
            for (;;) {
                unsigned v = KMAGIC;
                if (lane < 32)
                    v = __hip_atomic_load(&eflags[grp * 32 + lane],
                                          __ATOMIC_RELAXED, __HIP_MEMORY_SCOPE_AGENT);
                if (__ballot(v >= KMAGIC) == ~0ull) break;
                if (++polls > 4000000u) break;
                __builtin_amdgcn_s_sleep(2);
            }
        }
        asm volatile("" ::: "memory");       // acc reads must not hoist above poll
        __syncthreads();
        if (tid < 16) {
            float sv = __hip_atomic_load(&acc[(b0 + tid) * 16],
                                         __ATOMIC_RELAXED, __HIP_MEMORY_SCOPE_AGENT);
            float cv = __hip_atomic_load(&acc[2048 + (b0 + tid) * 16],
                                         __ATOMIC_RELAXED, __HIP_MEMORY_SCOPE_AGENT);
            float sm = sv * (1.0f / (float)KN);
            float cm = cv * (1.0f / (float)KN);
            out_coh[b0 + tid] = sqrtf(cm * cm + sm * sm);
        }
    }
}

extern "C" void kernel_launch(void* const* d_in, const int* in_sizes, int n_in,
                              void* d_out, int out_size, void* d_ws, size_t ws_size,
                              hipStream_t stream)
{
    (void)in_sizes; (void)n_in; (void)out_size; (void)ws_size;

    const float* theta0 = (const float*)d_in[0];
    const float* Kmat   = (const float*)d_in[1];
    const float* omega  = (const float*)d_in[2];
    const float* kg     = (const float*)d_in[3];

    float* out_theta = (float*)d_out;                    // 128*1024 f32
    float* out_coh   = out_theta + (size_t)KB * KN;      // +128 f32

    // ws: wave flags[2048] u32 @0 (8 KB) | eflags[256] @8192 | acc 16 KB
    //     @16384 | xbuf @32768: 3 rotating buffers of KB*KN dwords (512 KB ea).
    // Harness re-poisons ws with 0xAAAAAAAA each call: poison < KMAGIC, so
    // all protocol slots self-reset.
    unsigned* flags  = (unsigned*)d_ws;
    unsigned* eflags = (unsigned*)((char*)d_ws + 8192);
    float* acc       = (float*)((char*)d_ws + 16384);
    unsigned* xbuf   = (unsigned*)((char*)d_ws + 32768);

    k_main<<<256, 512, 0, stream>>>(theta0, Kmat, omega, kg,
                                    out_theta, out_coh, flags, eflags,
                                    acc, xbuf);
}

// Round 7
// 98.024 us; speedup vs baseline: 58955.9675x; 1.1317x over previous
//
#include <hip/hip_runtime.h>
#include <math.h>

#define KN 1024
#define KB 128
#define KDT 0.1f
#define KSTEPS 10
#define KMAGIC 0xB0000000u     // > 0xAAAAAAAA poison: stale poison never passes >=
#define PI_F 3.14159265358979f
#define TWO_PI_F 6.28318530717959f

typedef __attribute__((ext_vector_type(8))) short short8;
typedef __attribute__((ext_vector_type(4))) float floatx4;
typedef unsigned long long u64;

__device__ __forceinline__ unsigned short f2bf(float f) {
    unsigned u = __float_as_uint(f);
    u += 0x7FFF + ((u >> 16) & 1);          // round-to-nearest-even
    return (unsigned short)(u >> 16);
}

// X layout (fragment order, per group g = b>>4; 16384 dwords per group).
// Element (b15 = b&15, k): chunk=k>>5, quad=(k>>3)&3, jj=(k>>1)&3, p=k&1
//   dword idx = g*16384 + chunk*512 + jj*128 + quad*32 + b15*2 + p
// Chunk c is written entirely by producer block (g, ib=c) (its 32 cols).
// Consumer wave kq reads chunks kq*4..kq*4+3 -> depends on exactly 4 producers.
__device__ __forceinline__ unsigned xidx(int grp, int b15, int k) {
    return (unsigned)(grp * 16384 + (k >> 5) * 512 + ((k >> 1) & 3) * 128 +
                      ((k >> 3) & 3) * 32 + b15 * 2 + (k & 1));
}

// Single kernel, plain launch (graph-capturable).
// Grid 256 = 8 batch-groups(16 b) x 32 i-blocks(32 cols); block 512 thr = 8 waves.
// R7 = measured-best R0 structure VERBATIM (block flags set by tid0 after the
// block-wide drain barrier; consumers narrow-poll 4 flags = 16 B of one hot
// line; data loaded exactly once) + three ~zero-cost audited deltas:
//  (1) compiler fence after every poll: relaxed A-loads must not speculate
//      above the relaxed flag loads (legal reordering; best explanation of
//      R2's one-off post-timing divergence).
//  (2) THREE rotating X buffers (extra reuse-window margin; L3-resident).
//  (3) s_sleep(1) in the step poll (halved detection quantum).
// Dead ends (measured): per-wave flags = detect waits on max-over-32 store
// visibilities, +13 us (R6); data-polling floods fabric, FETCH 2-3x (R9/R3);
// sc0 globals are not cross-CU coherent primitives (R5, 5.8 s stalls).
__global__ __launch_bounds__(512)
void k_main(const float* __restrict__ theta0,
            const float* __restrict__ Kmat,
            const float* __restrict__ omega,
            const float* __restrict__ kg,
            float* __restrict__ out_theta,
            float* __restrict__ out_coh,
            unsigned* __restrict__ flags,        // 256 contiguous; group g = [g*32, g*32+32)
            float* __restrict__ acc,             // coherence accum: 2*128 slots, 64B stride
            unsigned* __restrict__ xbuf)         // 3 rotating buffers of KB*KN dwords
{
    const int grp = blockIdx.x >> 5;
    const int b0  = grp * 16;
    const int i0  = (blockIdx.x & 31) * 32;

    const int tid  = threadIdx.x;
    const int lane = tid & 63;
    const int kq   = tid >> 6;              // wave = k-eighth
    const int r16  = lane & 15;
    const int quad = lane >> 4;

    __shared__ float ldsY[8][2][16][34];    // [kq][S/C][m][il+pad] 34.8 KB

    // group leader zeroes its coherence accumulators (before publishing flag 0,
    // so every block's end-of-kernel atomicAdd is ordered after the zeroing)
    if ((blockIdx.x & 31) == 0 && tid < 16) {
        __hip_atomic_store(&acc[(b0 + tid) * 16], 0.f, __ATOMIC_RELAXED,
                           __HIP_MEMORY_SCOPE_AGENT);
        __hip_atomic_store(&acc[2048 + (b0 + tid) * 16], 0.f, __ATOMIC_RELAXED,
                           __HIP_MEMORY_SCOPE_AGENT);
    }

    // ---- B fragments (both wi) fp32->bf16 into registers; K symmetric.
    short8 bfrag[2][4];
    #pragma unroll
    for (int wi = 0; wi < 2; ++wi) {
        const float* kp = Kmat + (size_t)(i0 + wi * 16 + r16) * KN + kq * 128 + quad * 8;
        #pragma unroll
        for (int it = 0; it < 4; ++it) {
            const float4 v0 = *reinterpret_cast<const float4*>(kp + it * 32);
            const float4 v1 = *reinterpret_cast<const float4*>(kp + it * 32 + 4);
            short8 b_;
            b_[0] = (short)f2bf(v0.x); b_[1] = (short)f2bf(v0.y);
            b_[2] = (short)f2bf(v0.z); b_[3] = (short)f2bf(v0.w);
            b_[4] = (short)f2bf(v1.x); b_[5] = (short)f2bf(v1.y);
            b_[6] = (short)f2bf(v1.z); b_[7] = (short)f2bf(v1.w);
            bfrag[wi][it] = b_;
        }
    }

    // ---- per-thread theta state (block-private tile, 1 elem/thread).
    const int eb = b0 + (tid >> 5);          // batch
    const int ei = i0 + (tid & 31);          // column
    float th_reg = theta0[(size_t)eb * KN + ei];
    const float omg = omega[ei];
    float sn, cs;
    __sincosf(th_reg, &sn, &cs);
    unsigned* xb[3] = {xbuf, xbuf + (size_t)KB * KN, xbuf + 2 * (size_t)KB * KN};
    const unsigned xoff = xidx(grp, eb & 15, ei);
    __hip_atomic_store(&xb[0][xoff],
                       (unsigned)f2bf(sn) | ((unsigned)f2bf(cs) << 16),
                       __ATOMIC_RELAXED, __HIP_MEMORY_SCOPE_AGENT);
    const float scale = kg[0] * (1.0f / (float)KN);

    __syncthreads();                         // drain X(0) stores (vmcnt(0))
    if (tid == 0)
        __hip_atomic_store(&flags[blockIdx.x], KMAGIC + 0u,
                           __ATOMIC_RELAXED, __HIP_MEMORY_SCOPE_AGENT);

    // Per-wave dataflow wait: lanes 0..3 poll this wave's 4 producer flags
    // (contiguous -> single 128 B line). Monotone >= compare.
    auto wait_chunks = [&](unsigned tgt) {
        unsigned polls = 0;
        for (;;) {
            unsigned v = tgt;
            if (lane < 4)
                v = __hip_atomic_load(&flags[grp * 32 + kq * 4 + lane],
                                      __ATOMIC_RELAXED, __HIP_MEMORY_SCOPE_AGENT);
            if (__ballot(v >= tgt) == ~0ull) break;
            if (++polls > 4000000u) break;   // failsafe: fail visibly, not hang
            __builtin_amdgcn_s_sleep(1);
        }
        asm volatile("" ::: "memory");       // A-loads must not hoist above poll
    };

    float s2 = sn, c2 = cs;
    for (int s = 0; s < KSTEPS; ++s) {
        wait_chunks(KMAGIC + (unsigned)s);   // X(s) chunks for this wave ready

        // ---- A stage: 16 dense coherent u64 loads (512 B/wave-instr)
        const u64* xg = (const u64*)xb[s % 3] + grp * 8192 + kq * 1024 + lane;
        u64 aw[4][4];
        #pragma unroll
        for (int it = 0; it < 4; ++it)
            #pragma unroll
            for (int jj = 0; jj < 4; ++jj)
                aw[it][jj] = __hip_atomic_load((u64*)(xg + it * 256 + jj * 64),
                                               __ATOMIC_RELAXED,
                                               __HIP_MEMORY_SCOPE_AGENT);
        // ---- extract + MFMA (both wi subtiles)
        floatx4 accS[2] = {{0.f,0.f,0.f,0.f},{0.f,0.f,0.f,0.f}};
        floatx4 accC[2] = {{0.f,0.f,0.f,0.f},{0.f,0.f,0.f,0.f}};
        #pragma unroll
        for (int it = 0; it < 4; ++it) {
            short8 a_s, a_c;
            #pragma unroll
            for (int jj = 0; jj < 4; ++jj) {
                unsigned lo = (unsigned)aw[it][jj];
                unsigned hi = (unsigned)(aw[it][jj] >> 32);
                a_s[jj * 2]     = (short)(lo & 0xffffu);
                a_c[jj * 2]     = (short)(lo >> 16);
                a_s[jj * 2 + 1] = (short)(hi & 0xffffu);
                a_c[jj * 2 + 1] = (short)(hi >> 16);
            }
            #pragma unroll
            for (int wi = 0; wi < 2; ++wi) {
                accS[wi] = __builtin_amdgcn_mfma_f32_16x16x32_bf16(a_s, bfrag[wi][it], accS[wi], 0, 0, 0);
                accC[wi] = __builtin_amdgcn_mfma_f32_16x16x32_bf16(a_c, bfrag[wi][it], accC[wi], 0, 0, 0);
            }
        }
        #pragma unroll
        for (int wi = 0; wi < 2; ++wi)
            #pragma unroll
            for (int r = 0; r < 4; ++r) {
                ldsY[kq][0][quad * 4 + r][wi * 16 + r16] = accS[wi][r];  // D[m=quad*4+r][n=r16]
                ldsY[kq][1][quad * 4 + r][wi * 16 + r16] = accC[wi][r];
            }
        __syncthreads();

        // ---- Euler update + branch-wrap (1 elem/thread)
        {
            const int bl = tid >> 5, ilo = tid & 31;
            float Ys = 0.f, Yc = 0.f;
            #pragma unroll
            for (int q = 0; q < 8; ++q) {
                Ys += ldsY[q][0][bl][ilo];
                Yc += ldsY[q][1][bl][ilo];
            }
            const float coupling = cs * Ys - sn * Yc;   // sum_j K[i,j] sin(th_j - th_i)
            float tn = th_reg + KDT * (omg + scale * coupling);
            __sincosf(tn, &s2, &c2);                    // also next step's (sn,cs)
            if (tn > PI_F)       tn -= TWO_PI_F;        // == atan2f(s2,c2) to ~1e-7
            else if (tn < -PI_F) tn += TWO_PI_F;
            th_reg = tn;
            sn = s2; cs = c2;
        }
        if (s < KSTEPS - 1) {
            __hip_atomic_store(&xb[(s + 1) % 3][xoff],
                               (unsigned)f2bf(s2) | ((unsigned)f2bf(c2) << 16),
                               __ATOMIC_RELAXED, __HIP_MEMORY_SCOPE_AGENT);
            __syncthreads();                 // drain X(s+1) stores; guards ldsY reuse
            if (tid == 0)
                __hip_atomic_store(&flags[blockIdx.x], KMAGIC + (unsigned)(s + 1),
                                   __ATOMIC_RELAXED, __HIP_MEMORY_SCOPE_AGENT);
        } else {
            out_theta[(size_t)eb * KN + ei] = th_reg;
        }
    }

    // ---- coherence: block-local reduce over its 32 cols, then padded atomics
    __syncthreads();                         // epilogue ldsY reads done
    float* red = &ldsY[0][0][0][0];
    red[tid]       = s2;                     // == sin(theta_final) to ~1e-7
    red[512 + tid] = c2;
    __syncthreads();
    if (tid < 16) {
        float ss = 0.f, cc = 0.f;
        #pragma unroll
        for (int il2 = 0; il2 < 32; ++il2) {
            ss += red[tid * 32 + il2];
            cc += red[512 + tid * 32 + il2];
        }
        atomicAdd(&acc[(b0 + tid) * 16], ss);           // 64B-stride slots
        atomicAdd(&acc[2048 + (b0 + tid) * 16], cc);
    }
    __syncthreads();                         // drain atomics (vmcnt(0))
    if (tid == 0)
        __hip_atomic_store(&flags[blockIdx.x], KMAGIC + (unsigned)KSTEPS,
                           __ATOMIC_RELAXED, __HIP_MEMORY_SCOPE_AGENT);

    // group leader: wait all 32 blocks' adds, then write out_coh
    if ((blockIdx.x & 31) == 0) {
        if (tid < 64) {
            const unsigned tgt = KMAGIC + (unsigned)KSTEPS;
            unsigned polls = 0;
            for (;;) {
                unsigned v = tgt;
                if (lane < 32)
                    v = __hip_atomic_load(&flags[grp * 32 + lane],
                                          __ATOMIC_RELAXED, __HIP_MEMORY_SCOPE_AGENT);
                if (__ballot(v >= tgt) == ~0ull) break;
                if (++polls > 4000000u) break;
                __builtin_amdgcn_s_sleep(2);
            }
        }
        asm volatile("" ::: "memory");       // acc reads must not hoist above poll
        __syncthreads();
        if (tid < 16) {
            float sv = __hip_atomic_load(&acc[(b0 + tid) * 16],
                                         __ATOMIC_RELAXED, __HIP_MEMORY_SCOPE_AGENT);
            float cv = __hip_atomic_load(&acc[2048 + (b0 + tid) * 16],
                                         __ATOMIC_RELAXED, __HIP_MEMORY_SCOPE_AGENT);
            float sm = sv * (1.0f / (float)KN);
            float cm = cv * (1.0f / (float)KN);
            out_coh[b0 + tid] = sqrtf(cm * cm + sm * sm);
        }
    }
}

extern "C" void kernel_launch(void* const* d_in, const int* in_sizes, int n_in,
                              void* d_out, int out_size, void* d_ws, size_t ws_size,
                              hipStream_t stream)
{
    (void)in_sizes; (void)n_in; (void)out_size; (void)ws_size;

    const float* theta0 = (const float*)d_in[0];
    const float* Kmat   = (const float*)d_in[1];
    const float* omega  = (const float*)d_in[2];
    const float* kg     = (const float*)d_in[3];

    float* out_theta = (float*)d_out;                    // 128*1024 f32
    float* out_coh   = out_theta + (size_t)KB * KN;      // +128 f32

    // ws: flags[256] u32 @0 (1 KB) | acc 16 KB @4096 | xbuf @32768:
    //     3 rotating buffers of KB*KN dwords (512 KB each).
    // Harness re-poisons ws with 0xAAAAAAAA each call: poison < KMAGIC, so
    // all protocol slots self-reset.
    unsigned* flags = (unsigned*)d_ws;
    float* acc      = (float*)((char*)d_ws + 4096);
    unsigned* xbuf  = (unsigned*)((char*)d_ws + 32768);

    k_main<<<256, 512, 0, stream>>>(theta0, Kmat, omega, kg,
                                    out_theta, out_coh, flags, acc, xbuf);
}